// Round 12
// baseline (91.293 us; speedup 1.0000x reference)
//
#include <hip/hip_runtime.h>

typedef _Float16 f16;
typedef f16   f16x4 __attribute__((ext_vector_type(4)));
typedef f16   f16x8 __attribute__((ext_vector_type(8)));
typedef float f32x4 __attribute__((ext_vector_type(4)));

#define E 512
#define NT 16            /* K-steps of 32 */

// counted waitcnt + barrier (T4): N = loads allowed to stay in flight
#define WAIT_BAR(N) asm volatile("s_waitcnt vmcnt(" #N ")\n\ts_barrier" ::: "memory")
#define BAR()       asm volatile("s_barrier" ::: "memory")

// direct global->LDS async copy, 16B/lane; dst = wave-uniform base + lane*16
__device__ __forceinline__ void load_lds16(const void* g, void* l) {
    __builtin_amdgcn_global_load_lds(
        (const __attribute__((address_space(1))) unsigned int*)g,
        (__attribute__((address_space(3))) unsigned int*)l,
        16, 0, 0);
}

// ---------------------------------------------------------------------------
// prep: blocks 0..1023: x fp32 -> xm f16, XCD-BANDED (block b on XCD b%8
// converts the 4096-row band that gemm_q's XCD-b%8 blocks read -> each 4MB
// band L2-resident). blocks 1024..1055: Wq -> packed f16 [t][n][32] (for
// reg-side B loads), Wo -> row-major f16 (for gload_lds staging).
// ---------------------------------------------------------------------------
__global__ __launch_bounds__(256)
void prep_kernel(const float* __restrict__ X,
                 const float* __restrict__ Wq,
                 const float* __restrict__ Wo,
                 f16* __restrict__ xm,
                 f16* __restrict__ wq_p,
                 f16* __restrict__ wo_h) {
    const int b = blockIdx.x, tid = threadIdx.x;
    if (b < 1024) {
        const size_t row0 = (size_t)(b & 7) * 4096 + (size_t)(b >> 3) * 32;
        const float* src = X + row0 * E;
        f16* dst = xm + row0 * E;
#pragma unroll
        for (int g = 0; g < 8; ++g) {
            const int idx = (g * 256 + tid) * 8;
            float4 a = *(const float4*)(src + idx);
            float4 c = *(const float4*)(src + idx + 4);
            f16x8 h;
#pragma unroll
            for (int q = 0; q < 4; ++q) { h[q] = (f16)a[q]; h[4 + q] = (f16)c[q]; }
            *(f16x8*)(dst + idx) = h;
        }
    } else {
        const int bb = b - 1024;   // 0..31; 65536 8-elem groups total
#pragma unroll
        for (int g = 0; g < 8; ++g) {
            int grp = bb * 2048 + g * 256 + tid;
            if (grp < 32768) {                       // Wq -> packed
                const int n = grp >> 6, kg = grp & 63;
                const float* p = Wq + (size_t)n * E + kg * 8;
                float4 a = *(const float4*)p, c = *(const float4*)(p + 4);
                f16x8 h;
#pragma unroll
                for (int q = 0; q < 4; ++q) { h[q] = (f16)a[q]; h[4 + q] = (f16)c[q]; }
                const int t = kg >> 2, w = kg & 3;
                *(f16x8*)&wq_p[(size_t)t * 16384 + n * 32 + w * 8] = h;
            } else {                                 // Wo -> row-major
                grp -= 32768;
                const float* p = Wo + (size_t)grp * 8;
                float4 a = *(const float4*)p, c = *(const float4*)(p + 4);
                f16x8 h;
#pragma unroll
                for (int q = 0; q < 4; ++q) { h[q] = (f16)a[q]; h[4 + q] = (f16)c[q]; }
                *(f16x8*)(wo_h + (size_t)grp * 8) = h;
            }
        }
    }
}

// ---------------------------------------------------------------------------
// gemm_q: meas = cumprod8(cos(xm @ Wq^T)) written IN-PLACE over xm.
// One block = 128 rows x ALL 512 cols (rows block-private -> in-place legal:
// every global read of this block's rows drains at the final vmcnt(0)+barrier
// before any epilogue store). 1024 thr = 16 waves (mi=wave&1 m-half,
// nj=wave>>1 n-group); wave tile 64x64, acc[4][4], swapped-operand MFMA.
// A staged via gload_lds (waves 0-7, 1 chunk each), dbuf, counted vmcnt:
//   WAIT_BAR(5): stage(t+1) [1] + bw-refill(t+1) [4] stay in flight.
// B (packed Wq) in ping-pong regs bw0/bw1, refilled depth-2 (r8-verified).
// LDS 16KB; launch_bounds(1024,4) -> 1 block/CU, 4 waves/SIMD.
// ---------------------------------------------------------------------------
__global__ __launch_bounds__(1024, 4)
void gemm_q_kernel(f16* __restrict__ XM,          // xm: read rows, write meas
                   const f16* __restrict__ Wp) {  // packed [16][512][32]
    __shared__ __align__(16) f16 As[2][128 * 32]; // 8KB per buf

    const int tid  = threadIdx.x;
    const int lane = tid & 63;
    const int wave = tid >> 6;       // 0..15
    const int fr   = lane & 15;
    const int kq   = lane >> 4;
    const int mi   = wave & 1;
    const int nj   = wave >> 1;

    const int bid = blockIdx.x;                 // grid 256, %8==0
    const int chunk = gridDim.x >> 3;
    const int swz = (bid & 7) * chunk + (bid >> 3);
    const int m0 = swz * 128;

    auto stage = [&](int buf, int kt) {         // 8 x 1KB chunks, waves 0-7
        if (wave < 8) {
            const int G = wave * 64 + lane;     // granule: row=G>>2, colg=(G&3)*8
            const f16* src = XM + (size_t)(m0 + (G >> 2)) * E + kt * 32 + (G & 3) * 8;
            load_lds16(src, (char*)As[buf] + wave * 1024);
        }
    };

    const int nb = nj * 64;
    const f16* wbase = Wp + (size_t)(nb + fr) * 32 + kq * 8;

    f32x4 acc[4][4] = {};
    f16x8 bw0[4], bw1[4];

    stage(0, 0);
    stage(1, 1);
#pragma unroll
    for (int j = 0; j < 4; ++j) bw0[j] = *(const f16x8*)(wbase + j * 512);
#pragma unroll
    for (int j = 0; j < 4; ++j) bw1[j] = *(const f16x8*)(wbase + 16384 + j * 512);

#pragma unroll
    for (int t = 0; t < NT; ++t) {
        const int cur = t & 1;
        if (t + 1 < NT) { WAIT_BAR(5); } else { WAIT_BAR(0); }

        f16x8 afr[4];
#pragma unroll
        for (int i = 0; i < 4; ++i)
            afr[i] = *(const f16x8*)&As[cur][(mi * 64 + i * 16 + fr) * 32 + kq * 8];

#pragma unroll
        for (int i = 0; i < 4; ++i)
#pragma unroll
            for (int j = 0; j < 4; ++j)
                acc[i][j] = __builtin_amdgcn_mfma_f32_16x16x32_f16(
                    cur ? bw1[j] : bw0[j], afr[i], acc[i][j], 0, 0, 0);

        if (t + 2 < NT) {                        // refill consumed buffer
#pragma unroll
            for (int j = 0; j < 4; ++j) {
                f16x8 v = *(const f16x8*)(wbase + (size_t)(t + 2) * 16384 + j * 512);
                if (cur) bw1[j] = v; else bw0[j] = v;
            }
        }
        BAR();
        if (t + 2 < NT) stage(cur, t + 2);       // refill just-read LDS buffer
    }

    // epilogue (all reads drained): cumprod(cos) over 8-wide n-groups,
    // in-place f16x4 stores. m = lane&15, n = kq*4 + reg within 16.
#pragma unroll
    for (int i = 0; i < 4; ++i) {
        const int row = m0 + mi * 64 + i * 16 + fr;
#pragma unroll
        for (int j = 0; j < 4; ++j) {
            float c0 = __cosf(acc[i][j][0]);
            float c1 = c0 * __cosf(acc[i][j][1]);
            float c2 = c1 * __cosf(acc[i][j][2]);
            float c3 = c2 * __cosf(acc[i][j][3]);
            float ptot = __shfl_xor(c3, 16, 64); // partner holds other half
            float f = (kq & 1) ? ptot : 1.0f;    // odd quad = upper half
            f16x4 v = { (f16)(c0 * f), (f16)(c1 * f), (f16)(c2 * f), (f16)(c3 * f) };
            *(f16x4*)&XM[(size_t)row * E + nb + j * 16 + kq * 4] = v;
        }
    }
}

// ---------------------------------------------------------------------------
// gemm_o (r10-proven, verbatim): out = meas @ Wo^T, f32 output.
// Both operands staged via gload_lds, dbuf, WAIT_BAR(4), 4 blocks/CU.
// ---------------------------------------------------------------------------
__global__ __launch_bounds__(256, 4)
void gemm_o_kernel(const f16* __restrict__ A,
                   const f16* __restrict__ B,
                   float* __restrict__ Out) {
    __shared__ __align__(16) char As[2][128 * 32 * 2];
    __shared__ __align__(16) char Bs[2][128 * 32 * 2];

    const int tid  = threadIdx.x;
    const int lane = tid & 63;
    const int wave = tid >> 6;
    const int wm = (wave >> 1) * 64;
    const int wn = (wave & 1) * 64;
    const int fr = lane & 15;
    const int kq = lane >> 4;

    const int bid = blockIdx.x;                 // grid 1024
    const int chunk = gridDim.x >> 3;
    const int swz = (bid & 7) * chunk + (bid >> 3);
    const int m0 = (swz >> 2) * 128;
    const int n0 = (swz & 3) * 128;

    auto stage = [&](int buf, int kt) {         // 4 loads/wave (2 A + 2 B)
        const int k0 = kt * 32;
#pragma unroll
        for (int c = 0; c < 2; ++c) {
            const int ch = wave * 2 + c;
            const int G = ch * 64 + lane;
            const f16* srcA = A + (size_t)(m0 + (G >> 2)) * E + k0 + (G & 3) * 8;
            load_lds16(srcA, As[buf] + ch * 1024);
        }
#pragma unroll
        for (int c = 0; c < 2; ++c) {
            const int ch = wave * 2 + c;
            const int G = ch * 64 + lane;
            const f16* srcB = B + (size_t)(n0 + (G >> 2)) * E + k0 + (G & 3) * 8;
            load_lds16(srcB, Bs[buf] + ch * 1024);
        }
    };

    f32x4 acc[4][4] = {};

    stage(0, 0);
    stage(1, 1);

#pragma unroll
    for (int t = 0; t < NT; ++t) {
        const int cur = t & 1;
        if (t + 1 < NT) { WAIT_BAR(4); } else { WAIT_BAR(0); }

        f16x8 afr[4], bfr[4];
#pragma unroll
        for (int i = 0; i < 4; ++i)
            afr[i] = *(const f16x8*)&((const f16*)As[cur])[(wm + i * 16 + fr) * 32 + kq * 8];
#pragma unroll
        for (int j = 0; j < 4; ++j)
            bfr[j] = *(const f16x8*)&((const f16*)Bs[cur])[(wn + j * 16 + fr) * 32 + kq * 8];

#pragma unroll
        for (int i = 0; i < 4; ++i)
#pragma unroll
            for (int j = 0; j < 4; ++j)
                acc[i][j] = __builtin_amdgcn_mfma_f32_16x16x32_f16(
                    bfr[j], afr[i], acc[i][j], 0, 0, 0);

        BAR();
        if (t + 2 < NT) stage(cur, t + 2);
    }

#pragma unroll
    for (int i = 0; i < 4; ++i) {
        const int row = m0 + wm + i * 16 + fr;
#pragma unroll
        for (int j = 0; j < 4; ++j) {
            const int col = n0 + wn + j * 16 + kq * 4;
            *(f32x4*)&Out[(size_t)row * E + col] = acc[i][j];
        }
    }
}

// ---------------------------------------------------------------------------
extern "C" void kernel_launch(void* const* d_in, const int* in_sizes, int n_in,
                              void* d_out, int out_size, void* d_ws, size_t ws_size,
                              hipStream_t stream) {
    const float* x  = (const float*)d_in[0];
    const float* Wq = (const float*)d_in[1];
    // d_in[2]=Wk, d_in[3]=Wv: dead compute in the reference
    const float* Wo = (const float*)d_in[4];

    const int M = in_sizes[0] / E;   // 32768

    f16* wq_p = (f16*)d_ws;                  // 512 KB packed Wq
    f16* wo_h = wq_p + 512 * 512;            // 512 KB row-major Wo
    f16* xm   = wo_h + 512 * 512;            // 32 MB: xh, then meas (in-place)

    prep_kernel<<<1056, 256, 0, stream>>>(x, Wq, Wo, xm, wq_p, wo_h);
    gemm_q_kernel<<<M / 128, 1024, 0, stream>>>(xm, wq_p);          // 256 blocks
    gemm_o_kernel<<<(M / 128) * 4, 256, 0, stream>>>(xm, wo_h, (float*)d_out);
}

// Round 13
// 79.473 us; speedup vs baseline: 1.1487x; 1.1487x over previous
//
#include <hip/hip_runtime.h>

typedef _Float16 f16;
typedef f16   f16x4 __attribute__((ext_vector_type(4)));
typedef f16   f16x8 __attribute__((ext_vector_type(8)));
typedef float f32x4 __attribute__((ext_vector_type(4)));

#define E 512
#define NT 16            /* K-steps of 32 */

// counted waitcnt + barrier (T4): N = loads allowed to stay in flight
#define WAIT_BAR(N) asm volatile("s_waitcnt vmcnt(" #N ")\n\ts_barrier" ::: "memory")
#define BAR()       asm volatile("s_barrier" ::: "memory")

// direct global->LDS async copy, 16B/lane; dst = wave-uniform base + lane*16
__device__ __forceinline__ void load_lds16(const void* g, void* l) {
    __builtin_amdgcn_global_load_lds(
        (const __attribute__((address_space(1))) unsigned int*)g,
        (__attribute__((address_space(3))) unsigned int*)l,
        16, 0, 0);
}

// ---------------------------------------------------------------------------
// prep: x fp32 -> xh f16, Wq -> f16 row-major, Wo -> f16 row-major.
// Pure-BW grid-stride: 2112 blocks x 256 thr x 4 groups (8 f32 -> 8 f16).
// ---------------------------------------------------------------------------
__global__ __launch_bounds__(256)
void prep_kernel(const float* __restrict__ X,
                 const float* __restrict__ Wq,
                 const float* __restrict__ Wo,
                 f16* __restrict__ xh,
                 f16* __restrict__ wq_h,
                 f16* __restrict__ wo_h) {
    const int b = blockIdx.x, tid = threadIdx.x;
#pragma unroll
    for (int k = 0; k < 4; ++k) {
        int g = b * 1024 + k * 256 + tid;          // 8-elem group id
        const float* s; f16* d;
        if (g < 2097152)      { s = X;  d = xh;   }           // 32768*64 groups
        else if (g < 2129920) { s = Wq; d = wq_h; g -= 2097152; }
        else                  { s = Wo; d = wo_h; g -= 2129920; }
        const float* p = s + (size_t)g * 8;
        float4 a = *(const float4*)p, c = *(const float4*)(p + 4);
        f16x8 h;
#pragma unroll
        for (int q = 0; q < 4; ++q) { h[q] = (f16)a[q]; h[4 + q] = (f16)c[q]; }
        *(f16x8*)(d + (size_t)g * 8) = h;
    }
}

// ---------------------------------------------------------------------------
// GEMM core (r10 gemm_o, proven ~16us): C = A @ B^T, A,B f16 row-major [.,512].
// Both staged via gload_lds (linear f16 tiles), dbuf, counted-vmcnt schedule:
//   WAIT_BAR(4) -> ds_read + 16 MFMA (swapped operands) -> BAR -> stage(t+2).
// 256 thr = 4 waves (2x2), wave tile 64x64, LDS 32KB -> 4 blocks/CU
// (4 independent barrier domains per CU = stall slack; THE fast property).
// QUANTUM: epilogue cumprod8(cos()) (reg axis = n, partner lane^16), f16x4
// stores; else raw f32x4 stores.
// ---------------------------------------------------------------------------
template <bool QUANTUM>
__global__ __launch_bounds__(256, 4)
void gemm_kernel(const f16* __restrict__ A,
                 const f16* __restrict__ B,
                 void* __restrict__ Cptr) {
    __shared__ __align__(16) char As[2][128 * 32 * 2];   // 8KB/buf
    __shared__ __align__(16) char Bs[2][128 * 32 * 2];   // 8KB/buf

    const int tid  = threadIdx.x;
    const int lane = tid & 63;
    const int wave = tid >> 6;
    const int wm = (wave >> 1) * 64;
    const int wn = (wave & 1) * 64;
    const int fr = lane & 15;
    const int kq = lane >> 4;

    const int bid = blockIdx.x;                 // grid 1024, %8==0
    const int chunk = gridDim.x >> 3;
    const int swz = (bid & 7) * chunk + (bid >> 3);
    const int m0 = (swz >> 2) * 128;
    const int n0 = (swz & 3) * 128;

    auto stage = [&](int buf, int kt) {         // 4 loads/wave (2 A + 2 B)
        const int k0 = kt * 32;
#pragma unroll
        for (int c = 0; c < 2; ++c) {
            const int ch = wave * 2 + c;
            const int G = ch * 64 + lane;       // row=G>>2, colg=(G&3)*8
            const f16* srcA = A + (size_t)(m0 + (G >> 2)) * E + k0 + (G & 3) * 8;
            load_lds16(srcA, As[buf] + ch * 1024);
        }
#pragma unroll
        for (int c = 0; c < 2; ++c) {
            const int ch = wave * 2 + c;
            const int G = ch * 64 + lane;
            const f16* srcB = B + (size_t)(n0 + (G >> 2)) * E + k0 + (G & 3) * 8;
            load_lds16(srcB, Bs[buf] + ch * 1024);
        }
    };

    f32x4 acc[4][4] = {};

    stage(0, 0);
    stage(1, 1);

#pragma unroll
    for (int t = 0; t < NT; ++t) {
        const int cur = t & 1;
        if (t + 1 < NT) { WAIT_BAR(4); } else { WAIT_BAR(0); }

        f16x8 afr[4], bfr[4];
#pragma unroll
        for (int i = 0; i < 4; ++i)
            afr[i] = *(const f16x8*)&((const f16*)As[cur])[(wm + i * 16 + fr) * 32 + kq * 8];
#pragma unroll
        for (int j = 0; j < 4; ++j)
            bfr[j] = *(const f16x8*)&((const f16*)Bs[cur])[(wn + j * 16 + fr) * 32 + kq * 8];

        // swapped operands: m = lane&15, n = (lane>>4)*4 + reg
#pragma unroll
        for (int i = 0; i < 4; ++i)
#pragma unroll
            for (int j = 0; j < 4; ++j)
                acc[i][j] = __builtin_amdgcn_mfma_f32_16x16x32_f16(
                    bfr[j], afr[i], acc[i][j], 0, 0, 0);

        BAR();
        if (t + 2 < NT) stage(cur, t + 2);      // refill just-read buffer
    }

    if (QUANTUM) {
        // cumprod(cos) over 8-wide n-groups; partner = lane^16
        f16* C = (f16*)Cptr;
#pragma unroll
        for (int i = 0; i < 4; ++i) {
            const int row = m0 + wm + i * 16 + fr;
#pragma unroll
            for (int j = 0; j < 4; ++j) {
                float c0 = __cosf(acc[i][j][0]);
                float c1 = c0 * __cosf(acc[i][j][1]);
                float c2 = c1 * __cosf(acc[i][j][2]);
                float c3 = c2 * __cosf(acc[i][j][3]);
                float ptot = __shfl_xor(c3, 16, 64);
                float f = (kq & 1) ? ptot : 1.0f;   // odd quad = upper half
                f16x4 v = { (f16)(c0 * f), (f16)(c1 * f), (f16)(c2 * f), (f16)(c3 * f) };
                const int col = n0 + wn + j * 16 + kq * 4;
                *(f16x4*)&C[(size_t)row * E + col] = v;
            }
        }
    } else {
        float* C = (float*)Cptr;
#pragma unroll
        for (int i = 0; i < 4; ++i) {
            const int row = m0 + wm + i * 16 + fr;
#pragma unroll
            for (int j = 0; j < 4; ++j) {
                const int col = n0 + wn + j * 16 + kq * 4;
                *(f32x4*)&C[(size_t)row * E + col] = acc[i][j];
            }
        }
    }
}

// ======================= fallback path (r12, proven) =======================
__global__ __launch_bounds__(256)
void pack_wq_kernel(const f16* __restrict__ wq_h, f16* __restrict__ wq_p) {
    const int g = blockIdx.x * 256 + threadIdx.x;   // 32768 groups
    const int n = g >> 6, kg = g & 63;
    f16x8 v = *(const f16x8*)&wq_h[(size_t)n * E + kg * 8];
    const int t = kg >> 2, w = kg & 3;
    *(f16x8*)&wq_p[(size_t)t * 16384 + n * 32 + w * 8] = v;
}

__global__ __launch_bounds__(1024, 4)
void gemm_q_inplace_kernel(f16* __restrict__ XM, const f16* __restrict__ Wp) {
    __shared__ __align__(16) f16 As[2][128 * 32];

    const int tid  = threadIdx.x;
    const int lane = tid & 63;
    const int wave = tid >> 6;
    const int fr   = lane & 15;
    const int kq   = lane >> 4;
    const int mi   = wave & 1;
    const int nj   = wave >> 1;

    const int bid = blockIdx.x;
    const int chunk = gridDim.x >> 3;
    const int swz = (bid & 7) * chunk + (bid >> 3);
    const int m0 = swz * 128;

    auto stage = [&](int buf, int kt) {
        if (wave < 8) {
            const int G = wave * 64 + lane;
            const f16* src = XM + (size_t)(m0 + (G >> 2)) * E + kt * 32 + (G & 3) * 8;
            load_lds16(src, (char*)As[buf] + wave * 1024);
        }
    };

    const int nb = nj * 64;
    const f16* wbase = Wp + (size_t)(nb + fr) * 32 + kq * 8;

    f32x4 acc[4][4] = {};
    f16x8 bw0[4], bw1[4];

    stage(0, 0);
    stage(1, 1);
#pragma unroll
    for (int j = 0; j < 4; ++j) bw0[j] = *(const f16x8*)(wbase + j * 512);
#pragma unroll
    for (int j = 0; j < 4; ++j) bw1[j] = *(const f16x8*)(wbase + 16384 + j * 512);

#pragma unroll
    for (int t = 0; t < NT; ++t) {
        const int cur = t & 1;
        if (t + 1 < NT) { WAIT_BAR(5); } else { WAIT_BAR(0); }

        f16x8 afr[4];
#pragma unroll
        for (int i = 0; i < 4; ++i)
            afr[i] = *(const f16x8*)&As[cur][(mi * 64 + i * 16 + fr) * 32 + kq * 8];

#pragma unroll
        for (int i = 0; i < 4; ++i)
#pragma unroll
            for (int j = 0; j < 4; ++j)
                acc[i][j] = __builtin_amdgcn_mfma_f32_16x16x32_f16(
                    cur ? bw1[j] : bw0[j], afr[i], acc[i][j], 0, 0, 0);

        if (t + 2 < NT) {
#pragma unroll
            for (int j = 0; j < 4; ++j) {
                f16x8 v = *(const f16x8*)(wbase + (size_t)(t + 2) * 16384 + j * 512);
                if (cur) bw1[j] = v; else bw0[j] = v;
            }
        }
        BAR();
        if (t + 2 < NT) stage(cur, t + 2);
    }

#pragma unroll
    for (int i = 0; i < 4; ++i) {
        const int row = m0 + mi * 64 + i * 16 + fr;
#pragma unroll
        for (int j = 0; j < 4; ++j) {
            float c0 = __cosf(acc[i][j][0]);
            float c1 = c0 * __cosf(acc[i][j][1]);
            float c2 = c1 * __cosf(acc[i][j][2]);
            float c3 = c2 * __cosf(acc[i][j][3]);
            float ptot = __shfl_xor(c3, 16, 64);
            float f = (kq & 1) ? ptot : 1.0f;
            f16x4 v = { (f16)(c0 * f), (f16)(c1 * f), (f16)(c2 * f), (f16)(c3 * f) };
            *(f16x4*)&XM[(size_t)row * E + nb + j * 16 + kq * 4] = v;
        }
    }
}

// ---------------------------------------------------------------------------
extern "C" void kernel_launch(void* const* d_in, const int* in_sizes, int n_in,
                              void* d_out, int out_size, void* d_ws, size_t ws_size,
                              hipStream_t stream) {
    const float* x  = (const float*)d_in[0];
    const float* Wq = (const float*)d_in[1];
    // d_in[2]=Wk, d_in[3]=Wv: dead compute in the reference
    const float* Wo = (const float*)d_in[4];

    const int M = in_sizes[0] / E;   // 32768

    f16* wq_h = (f16*)d_ws;                       // 512 KB row-major
    f16* wo_h = wq_h + 512 * 512;                 // 512 KB row-major
    f16* wq_p = wo_h + 512 * 512;                 // 512 KB packed (fallback)
    f16* xh   = wq_p + 512 * 512;                 // 32 MB
    f16* meas = xh + (size_t)M * E;               // 32 MB (main path only)

    const size_t need_main = (size_t)(3 * 512 * 512 + 2 * (size_t)M * E) * sizeof(f16);

    prep_kernel<<<2112, 256, 0, stream>>>(x, Wq, Wo, xh, wq_h, wo_h);

    if (ws_size >= need_main) {
        // main: single-variable test — gemm_o structure + QUANTUM epilogue
        gemm_kernel<true><<<1024, 256, 0, stream>>>(xh, wq_h, meas);
        gemm_kernel<false><<<1024, 256, 0, stream>>>(meas, wo_h, (float*)d_out);
    } else {
        // fallback: r12-proven in-place path
        pack_wq_kernel<<<128, 256, 0, stream>>>(wq_h, wq_p);
        gemm_q_inplace_kernel<<<M / 128, 1024, 0, stream>>>(xh, wq_p);
        gemm_kernel<false><<<1024, 256, 0, stream>>>(xh, wo_h, (float*)d_out);
    }
}

// Round 14
// 74.957 us; speedup vs baseline: 1.2179x; 1.0602x over previous
//
#include <hip/hip_runtime.h>

typedef _Float16 f16;
typedef f16   f16x4 __attribute__((ext_vector_type(4)));
typedef f16   f16x8 __attribute__((ext_vector_type(8)));
typedef float f32x4 __attribute__((ext_vector_type(4)));

#define E 512
#define NT 16            /* K-steps of 32 */

// counted waitcnt + barrier (T4): N = loads allowed to stay in flight
#define WAIT_BAR(N) asm volatile("s_waitcnt vmcnt(" #N ")\n\ts_barrier" ::: "memory")
#define BAR()       asm volatile("s_barrier" ::: "memory")

// direct global->LDS async copy, 16B/lane; dst = wave-uniform base + lane*16
__device__ __forceinline__ void load_lds16(const void* g, void* l) {
    __builtin_amdgcn_global_load_lds(
        (const __attribute__((address_space(1))) unsigned int*)g,
        (__attribute__((address_space(3))) unsigned int*)l,
        16, 0, 0);
}

// ---------------------------------------------------------------------------
// Weight convert: Wq, Wo (fp32 [512][512]) -> f16 row-major copies (~1 MB)
// ---------------------------------------------------------------------------
__global__ __launch_bounds__(256)
void convert_w_kernel(const float* __restrict__ wq,
                      const float* __restrict__ wo,
                      f16* __restrict__ wq_h,
                      f16* __restrict__ wo_h) {
    int i = blockIdx.x * blockDim.x + threadIdx.x;
    const int n4 = (512 * 512) / 4;
    const float4* src; f16* dst;
    if (i < n4) { src = (const float4*)wq; dst = wq_h; }
    else        { src = (const float4*)wo; dst = wo_h; i -= n4; }
    float4 v = src[i];
    f16* p = dst + (size_t)i * 4;
    p[0] = (f16)v.x; p[1] = (f16)v.y; p[2] = (f16)v.z; p[3] = (f16)v.w;
}

// ---------------------------------------------------------------------------
// gemm_q: meas = cumprod8(cos(x @ Wq^T)).  Block = 64 rows x ALL 512 cols
// -> each x row read from HBM exactly ONCE (no prep pass, no xh).
// 512 thr = 8 waves; wave w owns n-cols [w*64,+64); wave tile 64x64,
// acc[4][4], swapped-operand MFMA (m = lane&15, n = (lane>>4)*4 + reg).
// A: raw fp32 via gload_lds, source-granule XOR swizzle (r10-verified:
//    slot(row,p) holds granule p^(row&7); fragment read = 2 swizzled f32x4
//    + cvt, 2-way banks). B: f16 Wq via gload_lds, linear (bank-uniform).
// LDS: B dbuf 64KB static + A dbuf 16KB dynamic = 80KB -> 2 blocks/CU
// (2 independent barrier domains = stall slack, unlike r12's lockstep).
// Schedule: WAIT_BAR(5) -> frag reads + 16 MFMA -> BAR -> stage(t+2).
// ---------------------------------------------------------------------------
__global__ __launch_bounds__(512, 4)
void gemm_q_kernel(const float* __restrict__ X,
                   const f16* __restrict__ B,     // Wq f16 row-major
                   f16* __restrict__ Meas) {
    __shared__ __align__(16) char Bs[2][512 * 32 * 2];  // 32KB/buf (static 64KB)
    extern __shared__ __align__(16) char As[];          // 2 x 8KB fp32 (dynamic)

    const int tid  = threadIdx.x;
    const int lane = tid & 63;
    const int wave = tid >> 6;       // 0..7
    const int fr   = lane & 15;
    const int kq   = lane >> 4;
    const int nb   = wave * 64;

    const int bid = blockIdx.x;                 // grid 512, %8==0
    const int chunk = gridDim.x >> 3;
    const int swz = (bid & 7) * chunk + (bid >> 3);
    const int m0 = swz * 64;

    auto stage = [&](int buf, int kt) {         // 5 loads/wave: 1 A + 4 B
        const int k0 = kt * 32;
        {   // A: 8 x 1KB chunks (64 rows x 128B), wave w -> chunk w
            const int s = wave * 64 + lane;     // granule slot
            const int row = s >> 3, p = s & 7;
            const int g = p ^ (row & 7);        // XOR-swizzled source granule
            const float* src = X + (size_t)(m0 + row) * E + k0 + g * 4;
            load_lds16(src, As + buf * 8192 + wave * 1024);
        }
#pragma unroll
        for (int c = 0; c < 4; ++c) {           // B: 32 x 1KB chunks
            const int ch = wave * 4 + c;
            const int G = ch * 64 + lane;       // n=G>>2, colg=(G&3)*8
            const f16* src = B + (size_t)(G >> 2) * E + k0 + (G & 3) * 8;
            load_lds16(src, Bs[buf] + ch * 1024);
        }
    };

    f32x4 acc[4][4] = {};

    stage(0, 0);
    stage(1, 1);

#pragma unroll
    for (int t = 0; t < NT; ++t) {
        const int cur = t & 1;
        if (t + 1 < NT) { WAIT_BAR(5); } else { WAIT_BAR(0); }

        f16x8 afr[4], bfr[4];
        const float* Af = (const float*)(As + cur * 8192);
#pragma unroll
        for (int i = 0; i < 4; ++i) {           // 2 swizzled f32x4 + cvt
            const int r = i * 16 + fr;
            const float* base = Af + r * 32;
            const int p0 = (kq * 2) ^ (r & 7);
            const int p1 = (kq * 2 + 1) ^ (r & 7);
            f32x4 a0 = *(const f32x4*)(base + p0 * 4);
            f32x4 a1 = *(const f32x4*)(base + p1 * 4);
#pragma unroll
            for (int q = 0; q < 4; ++q) { afr[i][q] = (f16)a0[q]; afr[i][4 + q] = (f16)a1[q]; }
        }
#pragma unroll
        for (int j = 0; j < 4; ++j)
            bfr[j] = *(const f16x8*)&((const f16*)Bs[cur])[(nb + j * 16 + fr) * 32 + kq * 8];

#pragma unroll
        for (int i = 0; i < 4; ++i)
#pragma unroll
            for (int j = 0; j < 4; ++j)
                acc[i][j] = __builtin_amdgcn_mfma_f32_16x16x32_f16(
                    bfr[j], afr[i], acc[i][j], 0, 0, 0);

        BAR();
        if (t + 2 < NT) stage(cur, t + 2);      // refill just-read buffers
    }

    // epilogue: cumprod(cos) over 8-wide n-groups; partner = lane^16
#pragma unroll
    for (int i = 0; i < 4; ++i) {
        const int row = m0 + i * 16 + fr;
#pragma unroll
        for (int j = 0; j < 4; ++j) {
            float c0 = __cosf(acc[i][j][0]);
            float c1 = c0 * __cosf(acc[i][j][1]);
            float c2 = c1 * __cosf(acc[i][j][2]);
            float c3 = c2 * __cosf(acc[i][j][3]);
            float ptot = __shfl_xor(c3, 16, 64);
            float f = (kq & 1) ? ptot : 1.0f;   // odd quad = upper half
            f16x4 v = { (f16)(c0 * f), (f16)(c1 * f), (f16)(c2 * f), (f16)(c3 * f) };
            *(f16x4*)&Meas[(size_t)row * E + nb + j * 16 + kq * 4] = v;
        }
    }
}

// ---------------------------------------------------------------------------
// gemm_o (r10/r13-proven, verbatim): out = meas @ Wo^T, fp32 output.
// Both staged via gload_lds, dbuf, WAIT_BAR(4), 4 blocks/CU. meas rows are
// XCD-matched to gemm_q's writer (same bid%8 -> same row band).
// ---------------------------------------------------------------------------
__global__ __launch_bounds__(256, 4)
void gemm_o_kernel(const f16* __restrict__ A,
                   const f16* __restrict__ B,
                   float* __restrict__ Out) {
    __shared__ __align__(16) char As[2][128 * 32 * 2];
    __shared__ __align__(16) char Bs[2][128 * 32 * 2];

    const int tid  = threadIdx.x;
    const int lane = tid & 63;
    const int wave = tid >> 6;
    const int wm = (wave >> 1) * 64;
    const int wn = (wave & 1) * 64;
    const int fr = lane & 15;
    const int kq = lane >> 4;

    const int bid = blockIdx.x;                 // grid 1024
    const int chunk = gridDim.x >> 3;
    const int swz = (bid & 7) * chunk + (bid >> 3);
    const int m0 = (swz >> 2) * 128;
    const int n0 = (swz & 3) * 128;

    auto stage = [&](int buf, int kt) {         // 4 loads/wave (2 A + 2 B)
        const int k0 = kt * 32;
#pragma unroll
        for (int c = 0; c < 2; ++c) {
            const int ch = wave * 2 + c;
            const int G = ch * 64 + lane;
            const f16* srcA = A + (size_t)(m0 + (G >> 2)) * E + k0 + (G & 3) * 8;
            load_lds16(srcA, As[buf] + ch * 1024);
        }
#pragma unroll
        for (int c = 0; c < 2; ++c) {
            const int ch = wave * 2 + c;
            const int G = ch * 64 + lane;
            const f16* srcB = B + (size_t)(n0 + (G >> 2)) * E + k0 + (G & 3) * 8;
            load_lds16(srcB, Bs[buf] + ch * 1024);
        }
    };

    f32x4 acc[4][4] = {};

    stage(0, 0);
    stage(1, 1);

#pragma unroll
    for (int t = 0; t < NT; ++t) {
        const int cur = t & 1;
        if (t + 1 < NT) { WAIT_BAR(4); } else { WAIT_BAR(0); }

        f16x8 afr[4], bfr[4];
#pragma unroll
        for (int i = 0; i < 4; ++i)
            afr[i] = *(const f16x8*)&((const f16*)As[cur])[(wm + i * 16 + fr) * 32 + kq * 8];
#pragma unroll
        for (int j = 0; j < 4; ++j)
            bfr[j] = *(const f16x8*)&((const f16*)Bs[cur])[(wn + j * 16 + fr) * 32 + kq * 8];

#pragma unroll
        for (int i = 0; i < 4; ++i)
#pragma unroll
            for (int j = 0; j < 4; ++j)
                acc[i][j] = __builtin_amdgcn_mfma_f32_16x16x32_f16(
                    bfr[j], afr[i], acc[i][j], 0, 0, 0);

        BAR();
        if (t + 2 < NT) stage(cur, t + 2);
    }

#pragma unroll
    for (int i = 0; i < 4; ++i) {
        const int row = m0 + wm + i * 16 + fr;
#pragma unroll
        for (int j = 0; j < 4; ++j) {
            const int col = n0 + wn + j * 16 + kq * 4;
            *(f32x4*)&Out[(size_t)row * E + col] = acc[i][j];
        }
    }
}

// ---------------------------------------------------------------------------
extern "C" void kernel_launch(void* const* d_in, const int* in_sizes, int n_in,
                              void* d_out, int out_size, void* d_ws, size_t ws_size,
                              hipStream_t stream) {
    const float* x  = (const float*)d_in[0];
    const float* Wq = (const float*)d_in[1];
    // d_in[2]=Wk, d_in[3]=Wv: dead compute in the reference
    const float* Wo = (const float*)d_in[4];

    const int M = in_sizes[0] / E;   // 32768

    f16* wq_h = (f16*)d_ws;                  // 512 KB
    f16* wo_h = wq_h + 512 * 512;            // 512 KB
    f16* meas = wo_h + 512 * 512;            // 32 MB

    convert_w_kernel<<<512, 256, 0, stream>>>(Wq, Wo, wq_h, wo_h);

    // gemm1 reads x fp32 directly (once), converts during fragment read
    gemm_q_kernel<<<M / 64, 512, 16 * 1024, stream>>>(x, wq_h, meas);  // 512 blocks
    gemm_o_kernel<<<(M / 128) * 4, 256, 0, stream>>>(meas, wo_h, (float*)d_out);
}